// Round 14
// baseline (499.884 us; speedup 1.0000x reference)
//
#include <hip/hip_runtime.h>
#include <hip/hip_bf16.h>

#define TOTAL   131072
#define DIMK    690
#define KPAD    704
#define KSTEPS  22
#define NCLASS  53
#define NTYPE   324
#define NCOLS   377
#define NPAD    384
#define NBAGS   8192
#define ALPHA   0.9f
#define TAU     1e-5f
#define FLAGCAP 32768
#define ZS      388
#define ROWS    32          // rows per k_main block (halved for occupancy)

typedef short  bf16x8 __attribute__((ext_vector_type(8)));
typedef float  f32x4  __attribute__((ext_vector_type(4)));

__device__ __forceinline__ unsigned short bf16_rne(float f) {
    unsigned int u = __float_as_uint(f);
    u = (u + 0x7fffu + ((u >> 16) & 1u)) >> 16;
    return (unsigned short)u;
}
__device__ __forceinline__ float bf16f(unsigned short h) {
    return __uint_as_float(((unsigned int)h) << 16);
}

// ---------------------------------------------------------------------------
// k_pack: W' = [liner_w | rel_w] (377x690 fp32) -> b-frag-major bf16 hi/lo,
// zero-padded to 384x704.
// ---------------------------------------------------------------------------
__global__ __launch_bounds__(256) void k_pack(const float* __restrict__ liner_w,
                                              const float* __restrict__ rel_w,
                                              unsigned short* __restrict__ whP,
                                              unsigned short* __restrict__ wlP) {
    const int id = blockIdx.x * 256 + threadIdx.x;
    if (id >= NPAD * KPAD) return;
    const int n = id / KPAD, k = id % KPAD;
    float v = 0.f;
    if (k < DIMK) {
        if (n < NTYPE)      v = liner_w[(size_t)n * DIMK + k];
        else if (n < NCOLS) v = rel_w[(size_t)(n - NTYPE) * DIMK + k];
    }
    const unsigned short hi = bf16_rne(v);
    const unsigned short lo = bf16_rne(v - bf16f(hi));
    const int t = n >> 4, col = n & 15, s = k >> 5, kk = k & 31;
    const int lane = (kk >> 3) * 16 + col, j = kk & 7;
    const int pidx = ((t * KSTEPS + s) * 64 + lane) * 8 + j;
    whP[pidx] = hi;
    wlP[pidx] = lo;
}

// ---------------------------------------------------------------------------
// k_table: table[s][q] = dot(type_weight[s], relation_weight[q])  fp32 exact
// ---------------------------------------------------------------------------
__global__ __launch_bounds__(256) void k_table(const float* __restrict__ tw,
                                               const float* __restrict__ rw,
                                               float* __restrict__ table) {
    const int pair = blockIdx.x * 4 + (threadIdx.x >> 6);
    const int lane = threadIdx.x & 63;
    if (pair >= NTYPE * NCLASS) return;
    const int s = pair / NCLASS;
    const int q = pair % NCLASS;
    const float* a = tw + (size_t)s * DIMK;
    const float* b = rw + (size_t)q * DIMK;
    float acc = 0.f;
    for (int k = lane; k < DIMK; k += 64) acc += a[k] * b[k];
#pragma unroll
    for (int off = 32; off; off >>= 1) acc += __shfl_xor(acc, off);
    if (lane == 0) table[pair] = acc;
}

// ---------------------------------------------------------------------------
// LDS union: A-staging (8 KB) overlaps the 8-row z-exchange (12.4 KB).
// The last K-step's lgkm barrier guarantees aS reads complete before the
// first epilogue scatter overwrites it.
// ---------------------------------------------------------------------------
union EpiU {
    unsigned short aS[2][2][1024];   // [buf][hi/lo][4 kblk][32 row][8] = 8 KB
    float          zS[8 * ZS];       // 12416 B
};

// ---------------------------------------------------------------------------
// Epilogue chunk H (0..3): 8 local rows [8H, 8H+8). MT = H>>1 (0..1),
// Q0 = (H&1)*2 selects the fragment-row half. All acc indexing static
// (rule #20). Each wave owns 48 cols (3 nt); after exchange, wave wv does
// row wv of the chunk.
// ---------------------------------------------------------------------------
template<int H>
__device__ __forceinline__ void epi8(f32x4 (&acc)[2][3],
                                     float* __restrict__ zS,
                                     const float* __restrict__ sB,
                                     const int* __restrict__ type_label,
                                     const int* __restrict__ query,
                                     const float* __restrict__ table,
                                     float* __restrict__ type_logits,
                                     float* __restrict__ att,
                                     float* __restrict__ xr,
                                     int* __restrict__ flagcnt,
                                     int* __restrict__ flaglist,
                                     int base, int wv, int ln) {
    constexpr int MT = H >> 1;
    constexpr int Q0 = (H & 1) * 2;
    const int q = ln >> 4;

    // ---- scatter this chunk's acc into zS[8][ZS] (cols wv*48..wv*48+47) ----
    if (q == Q0 || q == Q0 + 1) {
        const int lr0 = (q - Q0) * 4;
#pragma unroll
        for (int nt = 0; nt < 3; ++nt) {
            const int col = wv * 48 + nt * 16 + (ln & 15);
            const float bb = sB[col];
#pragma unroll
            for (int rg = 0; rg < 4; ++rg)
                zS[(lr0 + rg) * ZS + col] = acc[MT][nt][rg] + bb;
        }
    }
    asm volatile("s_waitcnt lgkmcnt(0)" ::: "memory");
    __builtin_amdgcn_s_barrier();

    // ---- wave wv processes row wv of this chunk ----
    const int grow = base + H * 8 + wv;
    const float* zrow = &zS[wv * ZS];

    float z[6];
#pragma unroll
    for (int j = 0; j < 6; ++j) {
        const int c = ln + 64 * j;
        z[j] = (c < NTYPE) ? zrow[c] : -INFINITY;
    }
    float m = -INFINITY;
#pragma unroll
    for (int j = 0; j < 6; ++j) m = fmaxf(m, z[j]);
#pragma unroll
    for (int off = 32; off; off >>= 1) m = fmaxf(m, __shfl_xor(m, off));

    float e[6];
    float ssum = 0.f;
#pragma unroll
    for (int j = 0; j < 6; ++j) {
        const int c = ln + 64 * j;
        e[j] = 0.f;
        if (c < NTYPE) { e[j] = __expf(z[j] - m); ssum += e[j]; }
    }
#pragma unroll
    for (int off = 32; off; off >>= 1) ssum += __shfl_xor(ssum, off);
    const float inv = 1.0f / ssum;           // == max(type_logits)

    const int label = type_label[grow];
    float bestv = -INFINITY;
    int   besti = NTYPE;
#pragma unroll
    for (int j = 0; j < 6; ++j) {
        const int c = ln + 64 * j;
        if (c < NTYPE) {
            const float p = e[j] * inv;
            type_logits[(size_t)grow * NTYPE + c] = p;
            const float v = p + ((c == label) ? ALPHA * inv : 0.f);
            if (v > bestv || (v == bestv && c < besti)) { bestv = v; besti = c; }
        }
    }
#pragma unroll
    for (int off = 32; off; off >>= 1) {
        const float ov = __shfl_xor(bestv, off);
        const int   oi = __shfl_xor(besti, off);
        if (ov > bestv || (ov == bestv && oi < besti)) { bestv = ov; besti = oi; }
    }

    // second-best nscore (for near-tie flag)
    float sv = -INFINITY;
#pragma unroll
    for (int j = 0; j < 6; ++j) {
        const int c = ln + 64 * j;
        if (c < NTYPE && c != besti) {
            const float v = e[j] * inv + ((c == label) ? ALPHA * inv : 0.f);
            sv = fmaxf(sv, v);
        }
    }
#pragma unroll
    for (int off = 32; off; off >>= 1) sv = fmaxf(sv, __shfl_xor(sv, off));

    if (ln == 0) {
        const int qq = query[grow];
        att[grow] = zrow[NTYPE + qq] + table[besti * NCLASS + qq];
        if (bestv - sv < TAU) {
            const int ix = atomicAdd(flagcnt, 1);
            if (ix < FLAGCAP) flaglist[ix] = grow;
        }
    }
    if (ln < NCLASS)
        xr[(size_t)grow * NCLASS + ln] = zrow[NTYPE + ln];

    asm volatile("s_waitcnt lgkmcnt(0)" ::: "memory");
    __builtin_amdgcn_s_barrier();   // zS free for next chunk
}

// ---------------------------------------------------------------------------
// k_main: 32 rows/block (occupancy lever: acc 48->24, ~76 regs/wave ->
// 3 blocks = 24 waves/CU vs 16), 8 waves, wave owns 3 nt. Split-bf16 MFMA
// (hh+hl+lh) over K=704, BK=32, lgkm-only barriers. Per-output-element math
// chain identical to round 8 -> bitwise-identical z, absmax 0.015625.
// ---------------------------------------------------------------------------
__global__ __launch_bounds__(512, 4) void k_main(const float* __restrict__ x,
                                                 const int* __restrict__ type_label,
                                                 const int* __restrict__ query,
                                                 const unsigned short* __restrict__ whP,
                                                 const unsigned short* __restrict__ wlP,
                                                 const float* __restrict__ liner_b,
                                                 const float* __restrict__ table,
                                                 float* __restrict__ type_logits,
                                                 float* __restrict__ att,
                                                 float* __restrict__ xr,
                                                 int* __restrict__ flagcnt,
                                                 int* __restrict__ flaglist) {
    __shared__ __align__(16) EpiU uni;
    __shared__ float sB[NPAD];

    const int tid  = threadIdx.x;
    const int base = blockIdx.x * ROWS;
    const int wv   = tid >> 6;      // 0..7
    const int ln   = tid & 63;

    const int srow  = tid >> 4;     // staging row 0..31
    const int kpart = tid & 15;     // staging k-pair 0..15 (2 floats each)

    f32x4 acc[2][3];
#pragma unroll
    for (int mt = 0; mt < 2; ++mt)
#pragma unroll
        for (int nt = 0; nt < 3; ++nt)
            acc[mt][nt] = (f32x4){0.f, 0.f, 0.f, 0.f};

    auto load_x = [&](int s, float (&dst)[2]) {
        const int k0 = s * 32 + kpart * 2;
        const float* xp = x + (size_t)(base + srow) * DIMK + k0;
        if (k0 + 2 <= DIMK) {
            const float2 p0 = *(const float2*)xp;
            dst[0] = p0.x; dst[1] = p0.y;
        } else {
            dst[0] = (k0 < DIMK) ? xp[0] : 0.f;
            dst[1] = 0.f;
        }
    };
    auto write_a = [&](int nb, const float (&src)[2]) {
        // layout: [kblk(4)][row(32)][8] shorts; thread covers j0..j0+1
        const int kb = kpart >> 2, j0 = (kpart & 3) * 2;
        const int widx = (kb * 32 + srow) * 8 + j0;
        const unsigned short h0 = bf16_rne(src[0]);
        const unsigned short h1 = bf16_rne(src[1]);
        const unsigned short l0 = bf16_rne(src[0] - bf16f(h0));
        const unsigned short l1 = bf16_rne(src[1] - bf16f(h1));
        *(unsigned*)&uni.aS[nb][0][widx] = (unsigned)h0 | ((unsigned)h1 << 16);
        *(unsigned*)&uni.aS[nb][1][widx] = (unsigned)l0 | ((unsigned)l1 << 16);
    };

    // prologue: stage k-step 0; bias to LDS
    float xv[2];
    load_x(0, xv);
    write_a(0, xv);
    for (int c = tid; c < NPAD; c += 512) sB[c] = (c < NTYPE) ? liner_b[c] : 0.f;
    asm volatile("s_waitcnt lgkmcnt(0)" ::: "memory");
    __builtin_amdgcn_s_barrier();

    const int aidx_base = ((ln >> 4) * 32 + (ln & 15)) * 8;
    for (int s = 0; s < KSTEPS; ++s) {
        const int cur = s & 1;
        float xn[2];
        if (s + 1 < KSTEPS) load_x(s + 1, xn);

        bf16x8 ah[2], al[2];
#pragma unroll
        for (int mt = 0; mt < 2; ++mt) {
            const int aidx = aidx_base + mt * 128;   // (mt*16 rows)*8
            ah[mt] = *(const bf16x8*)&uni.aS[cur][0][aidx];
            al[mt] = *(const bf16x8*)&uni.aS[cur][1][aidx];
        }
#pragma unroll
        for (int nt = 0; nt < 3; ++nt) {
            const int ntg = wv * 3 + nt;
            const size_t boff = ((size_t)(ntg * KSTEPS + s) * 64 + ln) * 8;
            const bf16x8 bh = *(const bf16x8*)(whP + boff);
            const bf16x8 bl = *(const bf16x8*)(wlP + boff);
#pragma unroll
            for (int mt = 0; mt < 2; ++mt) {
                acc[mt][nt] = __builtin_amdgcn_mfma_f32_16x16x32_bf16(ah[mt], bh, acc[mt][nt], 0, 0, 0);
                acc[mt][nt] = __builtin_amdgcn_mfma_f32_16x16x32_bf16(ah[mt], bl, acc[mt][nt], 0, 0, 0);
                acc[mt][nt] = __builtin_amdgcn_mfma_f32_16x16x32_bf16(al[mt], bh, acc[mt][nt], 0, 0, 0);
            }
        }
        if (s + 1 < KSTEPS) write_a(1 - cur, xn);
        // drain LDS ops only; global loads stay in flight across the barrier
        asm volatile("s_waitcnt lgkmcnt(0)" ::: "memory");
        __builtin_amdgcn_s_barrier();
    }

    // ---- epilogue: 4 chunks of 8 rows through the zS union ----
    epi8<0>(acc, uni.zS, sB, type_label, query, table, type_logits, att, xr, flagcnt, flaglist, base, wv, ln);
    epi8<1>(acc, uni.zS, sB, type_label, query, table, type_logits, att, xr, flagcnt, flaglist, base, wv, ln);
    epi8<2>(acc, uni.zS, sB, type_label, query, table, type_logits, att, xr, flagcnt, flaglist, base, wv, ln);
    epi8<3>(acc, uni.zS, sB, type_label, query, table, type_logits, att, xr, flagcnt, flaglist, base, wv, ln);
}

// ---------------------------------------------------------------------------
// k_fix: exact-fp32 recompute of argmax(nscore) for flagged rows; patch att.
// ---------------------------------------------------------------------------
__global__ __launch_bounds__(256) void k_fix(const float* __restrict__ x,
                                             const float* __restrict__ liner_w,
                                             const float* __restrict__ liner_b,
                                             const int* __restrict__ type_label,
                                             const int* __restrict__ query,
                                             const float* __restrict__ table,
                                             const float* __restrict__ xr,
                                             const int* __restrict__ flagcnt,
                                             const int* __restrict__ flaglist,
                                             float* __restrict__ att) {
    __shared__ float xs[704];   // padded, tail zeroed
    __shared__ float zs[NTYPE];
    __shared__ float redm[4];
    __shared__ float redv[4];
    __shared__ int   redi[4];
    const int tid = threadIdx.x;
    const int wv  = tid >> 6;
    const int ln  = tid & 63;
    int count = *flagcnt;
    if (count > FLAGCAP) count = FLAGCAP;

    for (int f = blockIdx.x; f < count; f += gridDim.x) {
        const int row = flaglist[f];
        __syncthreads();
        for (int k = tid; k < 704; k += 256) xs[k] = (k < DIMK) ? x[(size_t)row * DIMK + k] : 0.f;
        __syncthreads();

        for (int ci = 0; ci < 81; ++ci) {
            const int c = wv * 81 + ci;
            const float* w = liner_w + (size_t)c * DIMK;
            float acc = 0.f;
#pragma unroll
            for (int kk = 0; kk < 11; ++kk) {
                const int k = ln + kk * 64;
                const float wval = (k < DIMK) ? w[k] : 0.f;
                acc = fmaf(xs[k], wval, acc);
            }
#pragma unroll
            for (int off = 32; off; off >>= 1) acc += __shfl_xor(acc, off);
            if (ln == 0) zs[c] = acc + liner_b[c];
        }
        __syncthreads();

        float z0 = (tid < NTYPE) ? zs[tid] : -INFINITY;
        const int c1 = tid + 256;
        float z1 = (c1 < NTYPE) ? zs[c1] : -INFINITY;
        float m = fmaxf(z0, z1);
#pragma unroll
        for (int off = 32; off; off >>= 1) m = fmaxf(m, __shfl_xor(m, off));
        if (ln == 0) redm[wv] = m;
        __syncthreads();
        m = fmaxf(fmaxf(redm[0], redm[1]), fmaxf(redm[2], redm[3]));

        const int label = type_label[row];
        const float u0 = (tid < NTYPE) ? (__expf(z0 - m) + ((tid == label) ? ALPHA : 0.f)) : -1.f;
        const float u1 = (c1 < NTYPE)  ? (__expf(z1 - m) + ((c1 == label) ? ALPHA : 0.f))  : -1.f;
        float bv = u0; int bi = tid;
        if (u1 > bv) { bv = u1; bi = c1; }
#pragma unroll
        for (int off = 32; off; off >>= 1) {
            const float ov = __shfl_xor(bv, off);
            const int   oi = __shfl_xor(bi, off);
            if (ov > bv || (ov == bv && oi < bi)) { bv = ov; bi = oi; }
        }
        if (ln == 0) { redv[wv] = bv; redi[wv] = bi; }
        __syncthreads();
        if (tid == 0) {
            float fbv = redv[0]; int fbi = redi[0];
#pragma unroll
            for (int w = 1; w < 4; ++w) {
                if (redv[w] > fbv || (redv[w] == fbv && redi[w] < fbi)) {
                    fbv = redv[w]; fbi = redi[w];
                }
            }
            const int q = query[row];
            att[row] = xr[(size_t)row * NCLASS + q] + table[fbi * NCLASS + q];
        }
    }
}

// ---------------------------------------------------------------------------
// k_bag: per-bag segment softmax over att + weighted sum of xr + bias.
// ---------------------------------------------------------------------------
__global__ __launch_bounds__(64) void k_bag(const float* __restrict__ att,
                                            const float* __restrict__ xr,
                                            const int* __restrict__ scope,
                                            const float* __restrict__ bias,
                                            float* __restrict__ logits) {
    const int b = blockIdx.x;
    const int lane = threadIdx.x;
    const int s0 = scope[b];
    const int s1 = scope[b + 1];

    float m = -INFINITY;
    for (int i = s0 + lane; i < s1; i += 64) m = fmaxf(m, att[i]);
#pragma unroll
    for (int off = 32; off; off >>= 1) m = fmaxf(m, __shfl_xor(m, off));

    float sum = 0.f;
    float acc = 0.f;
    for (int i0 = s0; i0 < s1; i0 += 64) {
        const int n = min(64, s1 - i0);
        float e = 0.f;
        if (lane < n) e = __expf(att[i0 + lane] - m);
        float es = e;
#pragma unroll
        for (int off = 32; off; off >>= 1) es += __shfl_xor(es, off);
        sum += es;
        for (int j = 0; j < n; ++j) {
            const float ej = __shfl(e, j);
            if (lane < NCLASS) acc = fmaf(ej, xr[(size_t)(i0 + j) * NCLASS + lane], acc);
        }
    }
    const float inv = 1.0f / sum;
    if (lane < NCLASS) logits[b * NCLASS + lane] = acc * inv + bias[lane];
}

// ---------------------------------------------------------------------------
extern "C" void kernel_launch(void* const* d_in, const int* in_sizes, int n_in,
                              void* d_out, int out_size, void* d_ws, size_t ws_size,
                              hipStream_t stream) {
    const float* x          = (const float*)d_in[0];
    const int*   scope      = (const int*)d_in[1];
    const int*   type_label = (const int*)d_in[2];
    const int*   query      = (const int*)d_in[3];
    const float* rel_w      = (const float*)d_in[4];
    const float* type_w     = (const float*)d_in[5];
    const float* bias       = (const float*)d_in[6];
    const float* liner_w    = (const float*)d_in[7];
    const float* liner_b    = (const float*)d_in[8];

    float* logits      = (float*)d_out;                   // [8192 * 53]
    float* type_logits = (float*)d_out + NBAGS * NCLASS;  // [131072 * 324]

    float* ws = (float*)d_ws;
    float*          table    = ws;                               // 17172 (pad 17408)
    float*          att      = ws + 17408;                       // 131072
    float*          xr       = ws + 148480;                      // 131072*53
    unsigned short* whP      = (unsigned short*)(ws + 7095296);  // 270336 shorts
    unsigned short* wlP      = (unsigned short*)(ws + 7230464);  // 270336 shorts
    int*            flagcnt  = (int*)(ws + 7365632);
    int*            flaglist = (int*)(ws + 7365633);             // FLAGCAP ints

    hipMemsetAsync(flagcnt, 0, sizeof(int), stream);
    hipLaunchKernelGGL(k_pack, dim3((NPAD * KPAD + 255) / 256), dim3(256), 0, stream,
                       liner_w, rel_w, whP, wlP);
    hipLaunchKernelGGL(k_table, dim3((NTYPE * NCLASS + 3) / 4), dim3(256), 0, stream,
                       type_w, rel_w, table);
    hipLaunchKernelGGL(k_main, dim3(TOTAL / ROWS), dim3(512), 0, stream,
                       x, type_label, query, whP, wlP, liner_b, table,
                       type_logits, att, xr, flagcnt, flaglist);
    hipLaunchKernelGGL(k_fix, dim3(1024), dim3(256), 0, stream,
                       x, liner_w, liner_b, type_label, query, table, xr,
                       flagcnt, flaglist, att);
    hipLaunchKernelGGL(k_bag, dim3(NBAGS), dim3(64), 0, stream,
                       att, xr, scope, bias, logits);
}

// Round 15
// 435.221 us; speedup vs baseline: 1.1486x; 1.1486x over previous
//
#include <hip/hip_runtime.h>
#include <hip/hip_bf16.h>

#define TOTAL   131072
#define DIMK    690
#define KPAD    704
#define KSTEPS  22
#define NCLASS  53
#define NTYPE   324
#define NCOLS   377
#define NPAD    384
#define NBAGS   8192
#define ALPHA   0.9f
#define TAU     1e-5f
#define FLAGCAP 32768
#define ZS      388

typedef short  bf16x4 __attribute__((ext_vector_type(4)));
typedef short  bf16x8 __attribute__((ext_vector_type(8)));
typedef float  f32x4  __attribute__((ext_vector_type(4)));

__device__ __forceinline__ unsigned short bf16_rne(float f) {
    unsigned int u = __float_as_uint(f);
    u = (u + 0x7fffu + ((u >> 16) & 1u)) >> 16;
    return (unsigned short)u;
}
__device__ __forceinline__ float bf16f(unsigned short h) {
    return __uint_as_float(((unsigned int)h) << 16);
}

// ---------------------------------------------------------------------------
// k_pack: W' = [liner_w | rel_w] (377x690 fp32) -> b-frag-major bf16 hi/lo,
// zero-padded to 384x704.
// ---------------------------------------------------------------------------
__global__ __launch_bounds__(256) void k_pack(const float* __restrict__ liner_w,
                                              const float* __restrict__ rel_w,
                                              unsigned short* __restrict__ whP,
                                              unsigned short* __restrict__ wlP) {
    const int id = blockIdx.x * 256 + threadIdx.x;
    if (id >= NPAD * KPAD) return;
    const int n = id / KPAD, k = id % KPAD;
    float v = 0.f;
    if (k < DIMK) {
        if (n < NTYPE)      v = liner_w[(size_t)n * DIMK + k];
        else if (n < NCOLS) v = rel_w[(size_t)(n - NTYPE) * DIMK + k];
    }
    const unsigned short hi = bf16_rne(v);
    const unsigned short lo = bf16_rne(v - bf16f(hi));
    const int t = n >> 4, col = n & 15, s = k >> 5, kk = k & 31;
    const int lane = (kk >> 3) * 16 + col, j = kk & 7;
    const int pidx = ((t * KSTEPS + s) * 64 + lane) * 8 + j;
    whP[pidx] = hi;
    wlP[pidx] = lo;
}

// ---------------------------------------------------------------------------
// k_table: table[s][q] = dot(type_weight[s], relation_weight[q])  fp32 exact
// ---------------------------------------------------------------------------
__global__ __launch_bounds__(256) void k_table(const float* __restrict__ tw,
                                               const float* __restrict__ rw,
                                               float* __restrict__ table) {
    const int pair = blockIdx.x * 4 + (threadIdx.x >> 6);
    const int lane = threadIdx.x & 63;
    if (pair >= NTYPE * NCLASS) return;
    const int s = pair / NCLASS;
    const int q = pair % NCLASS;
    const float* a = tw + (size_t)s * DIMK;
    const float* b = rw + (size_t)q * DIMK;
    float acc = 0.f;
    for (int k = lane; k < DIMK; k += 64) acc += a[k] * b[k];
#pragma unroll
    for (int off = 32; off; off >>= 1) acc += __shfl_xor(acc, off);
    if (lane == 0) table[pair] = acc;
}

// ---------------------------------------------------------------------------
// Epilogue chunk H (0..7): 8 local rows [8H, 8H+8). MT = H>>1 is the acc
// m-tile; Q0 = (H&1)*2 selects which half of the 16 fragment rows. All acc
// indexing compile-time static (rule #20). zS = reinterpreted aS (12.4 KB).
// Each wave owns 48 cols (3 nt); after exchange, wave wv does row wv.
// ---------------------------------------------------------------------------
template<int H>
__device__ __forceinline__ void epi8(f32x4 (&acc)[4][3],
                                     float* __restrict__ zS,
                                     const float* __restrict__ sB,
                                     const int* __restrict__ type_label,
                                     const int* __restrict__ query,
                                     const float* __restrict__ table,
                                     float* __restrict__ type_logits,
                                     float* __restrict__ att,
                                     float* __restrict__ xr,
                                     int* __restrict__ flagcnt,
                                     int* __restrict__ flaglist,
                                     int base, int wv, int ln) {
    constexpr int MT = H >> 1;
    constexpr int Q0 = (H & 1) * 2;
    const int q = ln >> 4;

    // ---- scatter this chunk's acc into zS[8][ZS] (cols wv*48..wv*48+47) ----
    if (q == Q0 || q == Q0 + 1) {
        const int lr0 = (q - Q0) * 4;
#pragma unroll
        for (int nt = 0; nt < 3; ++nt) {
            const int col = wv * 48 + nt * 16 + (ln & 15);
            const float bb = sB[col];
#pragma unroll
            for (int rg = 0; rg < 4; ++rg)
                zS[(lr0 + rg) * ZS + col] = acc[MT][nt][rg] + bb;
        }
    }
    asm volatile("s_waitcnt lgkmcnt(0)" ::: "memory");
    __builtin_amdgcn_s_barrier();

    // ---- wave wv processes row wv of this chunk ----
    const int grow = base + H * 8 + wv;
    const float* zrow = &zS[wv * ZS];

    float z[6];
#pragma unroll
    for (int j = 0; j < 6; ++j) {
        const int c = ln + 64 * j;
        z[j] = (c < NTYPE) ? zrow[c] : -INFINITY;
    }
    float m = -INFINITY;
#pragma unroll
    for (int j = 0; j < 6; ++j) m = fmaxf(m, z[j]);
#pragma unroll
    for (int off = 32; off; off >>= 1) m = fmaxf(m, __shfl_xor(m, off));

    float e[6];
    float ssum = 0.f;
#pragma unroll
    for (int j = 0; j < 6; ++j) {
        const int c = ln + 64 * j;
        e[j] = 0.f;
        if (c < NTYPE) { e[j] = __expf(z[j] - m); ssum += e[j]; }
    }
#pragma unroll
    for (int off = 32; off; off >>= 1) ssum += __shfl_xor(ssum, off);
    const float inv = 1.0f / ssum;           // == max(type_logits)

    const int label = type_label[grow];
    float bestv = -INFINITY;
    int   besti = NTYPE;
#pragma unroll
    for (int j = 0; j < 6; ++j) {
        const int c = ln + 64 * j;
        if (c < NTYPE) {
            const float p = e[j] * inv;
            type_logits[(size_t)grow * NTYPE + c] = p;
            const float v = p + ((c == label) ? ALPHA * inv : 0.f);
            if (v > bestv || (v == bestv && c < besti)) { bestv = v; besti = c; }
        }
    }
#pragma unroll
    for (int off = 32; off; off >>= 1) {
        const float ov = __shfl_xor(bestv, off);
        const int   oi = __shfl_xor(besti, off);
        if (ov > bestv || (ov == bestv && oi < besti)) { bestv = ov; besti = oi; }
    }

    // second-best nscore (for near-tie flag)
    float sv = -INFINITY;
#pragma unroll
    for (int j = 0; j < 6; ++j) {
        const int c = ln + 64 * j;
        if (c < NTYPE && c != besti) {
            const float v = e[j] * inv + ((c == label) ? ALPHA * inv : 0.f);
            sv = fmaxf(sv, v);
        }
    }
#pragma unroll
    for (int off = 32; off; off >>= 1) sv = fmaxf(sv, __shfl_xor(sv, off));

    if (ln == 0) {
        const int qq = query[grow];
        att[grow] = zrow[NTYPE + qq] + table[besti * NCLASS + qq];
        if (bestv - sv < TAU) {
            const int ix = atomicAdd(flagcnt, 1);
            if (ix < FLAGCAP) flaglist[ix] = grow;
        }
    }
    if (ln < NCLASS)
        xr[(size_t)grow * NCLASS + ln] = zrow[NTYPE + ln];

    asm volatile("s_waitcnt lgkmcnt(0)" ::: "memory");
    __builtin_amdgcn_s_barrier();   // zS free for next chunk
}

// ---------------------------------------------------------------------------
// k_main: 64 rows/block, 8 waves (512 thr). Wave wv owns cols [48wv,48wv+48)
// (3 nt), acc = 4mt x 3nt x f32x4 = 48 AGPR. Split-bf16 MFMA (hh+hl+lh) over
// K=704; lgkm-only K-loop barriers (global loads ride across). Epilogue:
// 8 chunks of 8 rows exchanged through reused aS (LDS 17.9 KB).
// FINAL: best measured configuration (round 8: 438us; reproduced r13: 445us).
// Probes measured null/negative against this baseline: B register prefetch
// (r6, r9), BK=64 (r10), epilogue barrier reduction (r11), barrier-free
// direct-A (r12), occupancy doubling via half M-tile (r14).
// ---------------------------------------------------------------------------
__global__ __launch_bounds__(512, 4) void k_main(const float* __restrict__ x,
                                                 const int* __restrict__ type_label,
                                                 const int* __restrict__ query,
                                                 const unsigned short* __restrict__ whP,
                                                 const unsigned short* __restrict__ wlP,
                                                 const float* __restrict__ liner_b,
                                                 const float* __restrict__ table,
                                                 float* __restrict__ type_logits,
                                                 float* __restrict__ att,
                                                 float* __restrict__ xr,
                                                 int* __restrict__ flagcnt,
                                                 int* __restrict__ flaglist) {
    __shared__ unsigned short aS[2][2][2048];  // [buf][hi/lo][4 kblk][64 row][8]
    __shared__ float sB[NPAD];

    const int tid  = threadIdx.x;
    const int base = blockIdx.x * 64;
    const int wv   = tid >> 6;      // 0..7
    const int ln   = tid & 63;

    const int srow  = tid >> 3;     // staging row 0..63
    const int kpart = tid & 7;      // staging k-quad 0..7 (4 floats each)

    f32x4 acc[4][3];
#pragma unroll
    for (int mt = 0; mt < 4; ++mt)
#pragma unroll
        for (int nt = 0; nt < 3; ++nt)
            acc[mt][nt] = (f32x4){0.f, 0.f, 0.f, 0.f};

    auto load_x = [&](int s, float (&dst)[4]) {
        const int k0 = s * 32 + kpart * 4;
        const float* xp = x + (size_t)(base + srow) * DIMK + k0;
        if (k0 + 4 <= DIMK) {
            const float2 p0 = *(const float2*)(xp + 0);
            const float2 p1 = *(const float2*)(xp + 2);
            dst[0] = p0.x; dst[1] = p0.y; dst[2] = p1.x; dst[3] = p1.y;
        } else {
#pragma unroll
            for (int j = 0; j < 4; ++j) dst[j] = (k0 + j < DIMK) ? xp[j] : 0.f;
        }
    };
    auto write_a = [&](int nb, const float (&src)[4]) {
        // layout: [kblk][row][8] shorts; this thread covers j0..j0+3 of kblk
        const int kb = kpart >> 1, j0 = (kpart & 1) * 4;
        const int widx = (kb * 64 + srow) * 8 + j0;
        bf16x4 hv, lv;
#pragma unroll
        for (int j = 0; j < 4; ++j) {
            const unsigned short h = bf16_rne(src[j]);
            hv[j] = (short)h;
            lv[j] = (short)bf16_rne(src[j] - bf16f(h));
        }
        *(bf16x4*)&aS[nb][0][widx] = hv;
        *(bf16x4*)&aS[nb][1][widx] = lv;
    };

    // prologue
    float xv[4];
    load_x(0, xv);
    write_a(0, xv);
    for (int c = tid; c < NPAD; c += 512) sB[c] = (c < NTYPE) ? liner_b[c] : 0.f;
    asm volatile("s_waitcnt lgkmcnt(0)" ::: "memory");
    __builtin_amdgcn_s_barrier();

    const int aidx_base = ((ln >> 4) * 64 + (ln & 15)) * 8;
    for (int s = 0; s < KSTEPS; ++s) {
        const int cur = s & 1;
        float xn[4];
        if (s + 1 < KSTEPS) load_x(s + 1, xn);

        bf16x8 ah[4], al[4];
#pragma unroll
        for (int mt = 0; mt < 4; ++mt) {
            const int aidx = aidx_base + mt * 128;   // (mt*16)*8
            ah[mt] = *(const bf16x8*)&aS[cur][0][aidx];
            al[mt] = *(const bf16x8*)&aS[cur][1][aidx];
        }
#pragma unroll
        for (int nt = 0; nt < 3; ++nt) {
            const int ntg = wv * 3 + nt;
            const size_t boff = ((size_t)(ntg * KSTEPS + s) * 64 + ln) * 8;
            const bf16x8 bh = *(const bf16x8*)(whP + boff);
            const bf16x8 bl = *(const bf16x8*)(wlP + boff);
#pragma unroll
            for (int mt = 0; mt < 4; ++mt) {
                acc[mt][nt] = __builtin_amdgcn_mfma_f32_16x16x32_bf16(ah[mt], bh, acc[mt][nt], 0, 0, 0);
                acc[mt][nt] = __builtin_amdgcn_mfma_f32_16x16x32_bf16(ah[mt], bl, acc[mt][nt], 0, 0, 0);
                acc[mt][nt] = __builtin_amdgcn_mfma_f32_16x16x32_bf16(al[mt], bh, acc[mt][nt], 0, 0, 0);
            }
        }
        if (s + 1 < KSTEPS) write_a(1 - cur, xn);
        // drain LDS ops only; prefetch vmcnt loads stay in flight
        asm volatile("s_waitcnt lgkmcnt(0)" ::: "memory");
        __builtin_amdgcn_s_barrier();
    }

    // ---- epilogue: 8 chunks of 8 rows through reused aS ----
    float* zS = (float*)aS;   // 8*388*4 = 12416 B <= 16384 B
    epi8<0>(acc, zS, sB, type_label, query, table, type_logits, att, xr, flagcnt, flaglist, base, wv, ln);
    epi8<1>(acc, zS, sB, type_label, query, table, type_logits, att, xr, flagcnt, flaglist, base, wv, ln);
    epi8<2>(acc, zS, sB, type_label, query, table, type_logits, att, xr, flagcnt, flaglist, base, wv, ln);
    epi8<3>(acc, zS, sB, type_label, query, table, type_logits, att, xr, flagcnt, flaglist, base, wv, ln);
    epi8<4>(acc, zS, sB, type_label, query, table, type_logits, att, xr, flagcnt, flaglist, base, wv, ln);
    epi8<5>(acc, zS, sB, type_label, query, table, type_logits, att, xr, flagcnt, flaglist, base, wv, ln);
    epi8<6>(acc, zS, sB, type_label, query, table, type_logits, att, xr, flagcnt, flaglist, base, wv, ln);
    epi8<7>(acc, zS, sB, type_label, query, table, type_logits, att, xr, flagcnt, flaglist, base, wv, ln);
}

// ---------------------------------------------------------------------------
// k_fix: exact-fp32 recompute of argmax(nscore) for flagged rows; patch att.
// ---------------------------------------------------------------------------
__global__ __launch_bounds__(256) void k_fix(const float* __restrict__ x,
                                             const float* __restrict__ liner_w,
                                             const float* __restrict__ liner_b,
                                             const int* __restrict__ type_label,
                                             const int* __restrict__ query,
                                             const float* __restrict__ table,
                                             const float* __restrict__ xr,
                                             const int* __restrict__ flagcnt,
                                             const int* __restrict__ flaglist,
                                             float* __restrict__ att) {
    __shared__ float xs[704];   // padded, tail zeroed
    __shared__ float zs[NTYPE];
    __shared__ float redm[4];
    __shared__ float redv[4];
    __shared__ int   redi[4];
    const int tid = threadIdx.x;
    const int wv  = tid >> 6;
    const int ln  = tid & 63;
    int count = *flagcnt;
    if (count > FLAGCAP) count = FLAGCAP;

    for (int f = blockIdx.x; f < count; f += gridDim.x) {
        const int row = flaglist[f];
        __syncthreads();
        for (int k = tid; k < 704; k += 256) xs[k] = (k < DIMK) ? x[(size_t)row * DIMK + k] : 0.f;
        __syncthreads();

        for (int ci = 0; ci < 81; ++ci) {
            const int c = wv * 81 + ci;
            const float* w = liner_w + (size_t)c * DIMK;
            float acc = 0.f;
#pragma unroll
            for (int kk = 0; kk < 11; ++kk) {
                const int k = ln + kk * 64;
                const float wval = (k < DIMK) ? w[k] : 0.f;
                acc = fmaf(xs[k], wval, acc);
            }
#pragma unroll
            for (int off = 32; off; off >>= 1) acc += __shfl_xor(acc, off);
            if (ln == 0) zs[c] = acc + liner_b[c];
        }
        __syncthreads();

        float z0 = (tid < NTYPE) ? zs[tid] : -INFINITY;
        const int c1 = tid + 256;
        float z1 = (c1 < NTYPE) ? zs[c1] : -INFINITY;
        float m = fmaxf(z0, z1);
#pragma unroll
        for (int off = 32; off; off >>= 1) m = fmaxf(m, __shfl_xor(m, off));
        if (ln == 0) redm[wv] = m;
        __syncthreads();
        m = fmaxf(fmaxf(redm[0], redm[1]), fmaxf(redm[2], redm[3]));

        const int label = type_label[row];
        const float u0 = (tid < NTYPE) ? (__expf(z0 - m) + ((tid == label) ? ALPHA : 0.f)) : -1.f;
        const float u1 = (c1 < NTYPE)  ? (__expf(z1 - m) + ((c1 == label) ? ALPHA : 0.f))  : -1.f;
        float bv = u0; int bi = tid;
        if (u1 > bv) { bv = u1; bi = c1; }
#pragma unroll
        for (int off = 32; off; off >>= 1) {
            const float ov = __shfl_xor(bv, off);
            const int   oi = __shfl_xor(bi, off);
            if (ov > bv || (ov == bv && oi < bi)) { bv = ov; bi = oi; }
        }
        if (ln == 0) { redv[wv] = bv; redi[wv] = bi; }
        __syncthreads();
        if (tid == 0) {
            float fbv = redv[0]; int fbi = redi[0];
#pragma unroll
            for (int w = 1; w < 4; ++w) {
                if (redv[w] > fbv || (redv[w] == fbv && redi[w] < fbi)) {
                    fbv = redv[w]; fbi = redi[w];
                }
            }
            const int q = query[row];
            att[row] = xr[(size_t)row * NCLASS + q] + table[fbi * NCLASS + q];
        }
    }
}

// ---------------------------------------------------------------------------
// k_bag: per-bag segment softmax over att + weighted sum of xr + bias.
// ---------------------------------------------------------------------------
__global__ __launch_bounds__(64) void k_bag(const float* __restrict__ att,
                                            const float* __restrict__ xr,
                                            const int* __restrict__ scope,
                                            const float* __restrict__ bias,
                                            float* __restrict__ logits) {
    const int b = blockIdx.x;
    const int lane = threadIdx.x;
    const int s0 = scope[b];
    const int s1 = scope[b + 1];

    float m = -INFINITY;
    for (int i = s0 + lane; i < s1; i += 64) m = fmaxf(m, att[i]);
#pragma unroll
    for (int off = 32; off; off >>= 1) m = fmaxf(m, __shfl_xor(m, off));

    float sum = 0.f;
    float acc = 0.f;
    for (int i0 = s0; i0 < s1; i0 += 64) {
        const int n = min(64, s1 - i0);
        float e = 0.f;
        if (lane < n) e = __expf(att[i0 + lane] - m);
        float es = e;
#pragma unroll
        for (int off = 32; off; off >>= 1) es += __shfl_xor(es, off);
        sum += es;
        for (int j = 0; j < n; ++j) {
            const float ej = __shfl(e, j);
            if (lane < NCLASS) acc = fmaf(ej, xr[(size_t)(i0 + j) * NCLASS + lane], acc);
        }
    }
    const float inv = 1.0f / sum;
    if (lane < NCLASS) logits[b * NCLASS + lane] = acc * inv + bias[lane];
}

// ---------------------------------------------------------------------------
extern "C" void kernel_launch(void* const* d_in, const int* in_sizes, int n_in,
                              void* d_out, int out_size, void* d_ws, size_t ws_size,
                              hipStream_t stream) {
    const float* x          = (const float*)d_in[0];
    const int*   scope      = (const int*)d_in[1];
    const int*   type_label = (const int*)d_in[2];
    const int*   query      = (const int*)d_in[3];
    const float* rel_w      = (const float*)d_in[4];
    const float* type_w     = (const float*)d_in[5];
    const float* bias       = (const float*)d_in[6];
    const float* liner_w    = (const float*)d_in[7];
    const float* liner_b    = (const float*)d_in[8];

    float* logits      = (float*)d_out;                   // [8192 * 53]
    float* type_logits = (float*)d_out + NBAGS * NCLASS;  // [131072 * 324]

    float* ws = (float*)d_ws;
    float*          table    = ws;                               // 17172 (pad 17408)
    float*          att      = ws + 17408;                       // 131072
    float*          xr       = ws + 148480;                      // 131072*53
    unsigned short* whP      = (unsigned short*)(ws + 7095296);  // 270336 shorts
    unsigned short* wlP      = (unsigned short*)(ws + 7230464);  // 270336 shorts
    int*            flagcnt  = (int*)(ws + 7365632);
    int*            flaglist = (int*)(ws + 7365633);             // FLAGCAP ints

    hipMemsetAsync(flagcnt, 0, sizeof(int), stream);
    hipLaunchKernelGGL(k_pack, dim3((NPAD * KPAD + 255) / 256), dim3(256), 0, stream,
                       liner_w, rel_w, whP, wlP);
    hipLaunchKernelGGL(k_table, dim3((NTYPE * NCLASS + 3) / 4), dim3(256), 0, stream,
                       type_w, rel_w, table);
    hipLaunchKernelGGL(k_main, dim3(TOTAL / 64), dim3(512), 0, stream,
                       x, type_label, query, whP, wlP, liner_b, table,
                       type_logits, att, xr, flagcnt, flaglist);
    hipLaunchKernelGGL(k_fix, dim3(1024), dim3(256), 0, stream,
                       x, liner_w, liner_b, type_label, query, table, xr,
                       flagcnt, flaglist, att);
    hipLaunchKernelGGL(k_bag, dim3(NBAGS), dim3(64), 0, stream,
                       att, xr, scope, bias, logits);
}